// Round 5
// baseline (696.502 us; speedup 1.0000x reference)
//
#include <hip/hip_runtime.h>

#define N_NODES 100000
#define N_EDGES 1600000
#define NB_SCAN 391   // ceil(N_NODES / 256)
#define R_REP 8       // one histogram replica per XCD

// ---------------- XCD-pinned, L2-cached degree counting ----------------
// Device-scope atomics bypass L2 (execute at MALL, ~26G ops/s, write-through:
// R4 counters showed WRITE_SIZE == 32B * n_atomics). Workgroup-scope atomics
// stay cached in the XCD-local L2. Safe because replica index = XCC_ID, so
// each counter address is only ever touched by one XCD's L2; kernel-end
// release writes the L2 back before the reduce kernel reads it.

__device__ __forceinline__ int xcc_id() {
    int x;
    asm("s_getreg_b32 %0, hwreg(HW_REG_XCC_ID)" : "=s"(x));
    return x & (R_REP - 1);
}

__global__ void deg_rep_kernel(const int* __restrict__ src, const int* __restrict__ dst,
                               unsigned int* __restrict__ degO, unsigned int* __restrict__ degI) {
    int xcc = xcc_id();
    unsigned int* mO = degO + (size_t)xcc * N_NODES;
    unsigned int* mI = degI + (size_t)xcc * N_NODES;
    int i = blockIdx.x * blockDim.x + threadIdx.x;
    int stride = gridDim.x * blockDim.x;
    for (int e = i; e < N_EDGES; e += stride) {
        __hip_atomic_fetch_add(&mO[src[e]], 1u, __ATOMIC_RELAXED, __HIP_MEMORY_SCOPE_WORKGROUP);
        __hip_atomic_fetch_add(&mI[dst[e]], 1u, __ATOMIC_RELAXED, __HIP_MEMORY_SCOPE_WORKGROUP);
    }
}

// reduce replicas -> norms (rsqrt fused) + int in-degree for the scan
__global__ void reduce_norm_kernel(const unsigned int* __restrict__ degO,
                                   const unsigned int* __restrict__ degI,
                                   float* __restrict__ norm_src, float* __restrict__ norm_dst,
                                   int* __restrict__ deg_int) {
    int n = blockIdx.x * blockDim.x + threadIdx.x;
    if (n >= N_NODES) return;
    unsigned int so = 0, si = 0;
#pragma unroll
    for (int r = 0; r < R_REP; ++r) {
        so += degO[(size_t)r * N_NODES + n];
        si += degI[(size_t)r * N_NODES + n];
    }
    norm_src[n] = rsqrtf(fmaxf((float)so, 1.0f));
    norm_dst[n] = rsqrtf(fmaxf((float)si, 1.0f));
    deg_int[n] = (int)si;
}

// ---------------- 3-phase device-wide exclusive scan of in-degrees ----------------

__global__ void block_sum_kernel(const int* __restrict__ deg_in, int* __restrict__ block_sums) {
    __shared__ int sdata[256];
    int t = threadIdx.x;
    int n = blockIdx.x * 256 + t;
    int v = (n < N_NODES) ? deg_in[n] : 0;
    sdata[t] = v;
    __syncthreads();
    for (int off = 128; off > 0; off >>= 1) {
        if (t < off) sdata[t] += sdata[t + off];
        __syncthreads();
    }
    if (t == 0) block_sums[blockIdx.x] = sdata[0];
}

__global__ void scan_blocks_kernel(const int* __restrict__ block_sums, int* __restrict__ block_off) {
    __shared__ int part[512];
    int t = threadIdx.x;
    int v = (t < NB_SCAN) ? block_sums[t] : 0;
    part[t] = v;
    __syncthreads();
    for (int off = 1; off < 512; off <<= 1) {
        int u = (t >= off) ? part[t - off] : 0;
        __syncthreads();
        part[t] += u;
        __syncthreads();
    }
    if (t < NB_SCAN) block_off[t] = part[t] - v;   // exclusive
}

__global__ void scatter_rowptr_kernel(const int* __restrict__ deg_in,
                                      const int* __restrict__ block_off,
                                      int* __restrict__ row_ptr, int* __restrict__ cursor) {
    __shared__ int part[256];
    int t = threadIdx.x;
    int n = blockIdx.x * 256 + t;
    int v = (n < N_NODES) ? deg_in[n] : 0;
    part[t] = v;
    __syncthreads();
    for (int off = 1; off < 256; off <<= 1) {
        int u = (t >= off) ? part[t - off] : 0;
        __syncthreads();
        part[t] += u;
        __syncthreads();
    }
    int excl = part[t] - v + block_off[blockIdx.x];
    if (n < N_NODES) { row_ptr[n] = excl; cursor[n] = excl; }
    if (n == N_NODES - 1) row_ptr[N_NODES] = excl + v;
}

// fill CSR-by-dst: packed (src, coef) per edge (cursor stays device-scope:
// slot assignment must be globally unique across XCDs)
__global__ void fill_kernel(const int* __restrict__ src, const int* __restrict__ dst,
                            const float* __restrict__ ew,
                            const float* __restrict__ ns, const float* __restrict__ nd,
                            int* __restrict__ cursor, int2* __restrict__ epack) {
    int i = blockIdx.x * blockDim.x + threadIdx.x;
    int stride = gridDim.x * blockDim.x;
    for (int e = i; e < N_EDGES; e += stride) {
        int s = src[e];
        int d = dst[e];
        float c = ns[s] * ew[e] * nd[d];
        int p = atomicAdd(&cursor[d], 1);
        epack[p] = make_int2(s, __float_as_int(c));
    }
}

// ---------------- dense transform: h = act(x [+b]) @ W ----------------

template <int DOUT, bool BIAS_RELU>
__global__ void matmul_kernel(const float* __restrict__ x, const float* __restrict__ W,
                              const float* __restrict__ bin, float* __restrict__ h) {
    __shared__ float Wl[64 * DOUT];
    int tid = threadIdx.x;
    for (int i = tid; i < 64 * DOUT; i += blockDim.x) Wl[i] = W[i];
    __syncthreads();

    int lane = tid & 63;
    int wid = tid >> 6;
    int wglobal = blockIdx.x * 4 + wid;
    int nwaves = gridDim.x * 4;
    int olane = lane & (DOUT - 1);

    float bv = 0.0f;
    if (BIAS_RELU) bv = bin[lane];

    for (int n = wglobal; n < N_NODES; n += nwaves) {
        float xv = x[n * 64 + lane];
        if (BIAS_RELU) xv = fmaxf(xv + bv, 0.0f);
        float acc = 0.0f;
#pragma unroll
        for (int k = 0; k < 64; ++k) {
            float xk = __shfl(xv, k);
            acc += xk * Wl[k * DOUT + olane];
        }
        if (lane < DOUT) h[n * DOUT + lane] = acc;
    }
}

// ---------------- CSR aggregation ----------------

template <int D, bool FINAL>
__global__ void csr_agg_kernel(const int* __restrict__ row_ptr,
                               const int2* __restrict__ epack,
                               const float* __restrict__ h,
                               const float* __restrict__ bias, float* __restrict__ out) {
    int tid = blockIdx.x * blockDim.x + threadIdx.x;
    int stride = gridDim.x * blockDim.x;
    int lane = threadIdx.x & (D - 1);
    int node0 = tid / D;
    int nstride = stride / D;
    for (int n = node0; n < N_NODES; n += nstride) {
        int s = row_ptr[n];
        int e = row_ptr[n + 1];
        float acc = 0.0f;
        int i = s;
        for (; i + 3 < e; i += 4) {
            int2 v0 = epack[i], v1 = epack[i + 1], v2 = epack[i + 2], v3 = epack[i + 3];
            float h0 = h[v0.x * D + lane];
            float h1 = h[v1.x * D + lane];
            float h2 = h[v2.x * D + lane];
            float h3 = h[v3.x * D + lane];
            acc += h0 * __int_as_float(v0.y) + h1 * __int_as_float(v1.y)
                 + h2 * __int_as_float(v2.y) + h3 * __int_as_float(v3.y);
        }
        for (; i < e; ++i) {
            int2 v = epack[i];
            acc += h[v.x * D + lane] * __int_as_float(v.y);
        }
        if (FINAL) out[n * D + lane] = acc + bias[lane];
        else       out[n * D + lane] = acc;
    }
}

extern "C" void kernel_launch(void* const* d_in, const int* in_sizes, int n_in,
                              void* d_out, int out_size, void* d_ws, size_t ws_size,
                              hipStream_t stream) {
    const float* features = (const float*)d_in[0];
    const float* ew       = (const float*)d_in[1];
    const int*   src      = (const int*)d_in[2];
    const int*   dst      = (const int*)d_in[3];
    const float* W1       = (const float*)d_in[4];
    const float* b1       = (const float*)d_in[5];
    const float* W2       = (const float*)d_in[6];
    const float* b2       = (const float*)d_in[7];
    const float* Wp       = (const float*)d_in[8];
    const float* bp       = (const float*)d_in[9];
    float* out = (float*)d_out;

    // workspace layout (4B units)
    float* ws        = (float*)d_ws;
    float* norm_src  = ws;                              // N
    float* norm_dst  = ws + N_NODES;                    // N
    int*   deg_int   = (int*)(ws + 2 * N_NODES);        // N
    int*   row_ptr   = deg_int + N_NODES;               // N+1
    int*   cursor    = row_ptr + (N_NODES + 1);         // N
    int*   block_sums= cursor + N_NODES;                // NB_SCAN
    int*   block_off = block_sums + NB_SCAN;            // NB_SCAN
    int2*  epack     = (int2*)(block_off + NB_SCAN + 1);// E int2 (offset even -> 8B aligned)
    float* bufA      = (float*)(epack + N_EDGES);       // N*64
    float* bufB      = bufA + N_NODES * 64;             // N*64

    // degree replicas alias bufA (dead until agg1 writes it): 2 * R_REP * N uints = 6.4 MB
    // (each replica is 400000 B = 3125 * 128 B -> no L2 line straddles replicas)
    unsigned int* degO = (unsigned int*)bufA;
    unsigned int* degI = degO + (size_t)R_REP * N_NODES;

    // ---- CSR + coef build (reused by all 3 layers) ----
    hipMemsetAsync(degO, 0, 2 * (size_t)R_REP * N_NODES * sizeof(unsigned int), stream);
    deg_rep_kernel<<<2048, 256, 0, stream>>>(src, dst, degO, degI);
    reduce_norm_kernel<<<NB_SCAN, 256, 0, stream>>>(degO, degI, norm_src, norm_dst, deg_int);
    block_sum_kernel<<<NB_SCAN, 256, 0, stream>>>(deg_int, block_sums);
    scan_blocks_kernel<<<1, 512, 0, stream>>>(block_sums, block_off);
    scatter_rowptr_kernel<<<NB_SCAN, 256, 0, stream>>>(deg_int, block_off, row_ptr, cursor);
    fill_kernel<<<2048, 256, 0, stream>>>(src, dst, ew, norm_src, norm_dst, cursor, epack);

    // ---- layer 1: bufA = A * (features @ W1)   (bias+relu deferred)
    matmul_kernel<64, false><<<1024, 256, 0, stream>>>(features, W1, nullptr, bufB);
    csr_agg_kernel<64, false><<<4096, 256, 0, stream>>>(row_ptr, epack, bufB, nullptr, bufA);

    // ---- layer 2: bufA = A * (relu(bufA + b1) @ W2)
    matmul_kernel<64, true><<<1024, 256, 0, stream>>>(bufA, W2, b1, bufB);
    csr_agg_kernel<64, false><<<4096, 256, 0, stream>>>(row_ptr, epack, bufB, nullptr, bufA);

    // ---- layer 3: out = A * (relu(bufA + b2) @ Wp) + bp
    matmul_kernel<32, true><<<1024, 256, 0, stream>>>(bufA, Wp, b2, bufB);
    csr_agg_kernel<32, true><<<4096, 256, 0, stream>>>(row_ptr, epack, bufB, bp, out);
}

// Round 6
// 534.910 us; speedup vs baseline: 1.3021x; 1.3021x over previous
//
#include <hip/hip_runtime.h>

#define N_NODES 100000
#define N_EDGES 1600000
#define NB_SCAN 391    // ceil(N_NODES / 256)
#define NSLICE 64      // edge slices
#define SLICE_E 25000  // N_EDGES / NSLICE
#define NBUCK 4        // node buckets
#define BUCK_N 25000   // nodes per bucket (N_NODES / NBUCK)
#define BUCK_W 12500   // uint32 words per bucket (2x uint16 packed)

// ---------------- LDS-bucketed histogram (no global atomics) ----------------
// Block (slice s, bucket b): count occurrences of ids[] within bucket b over
// edge slice s using packed-16-bit LDS atomics. For RANK: record each edge's
// rank within (slice, node) from the atomic return. Flush = plain writes.

template <bool RANK>
__global__ void __launch_bounds__(512) count_kernel(
        const int* __restrict__ ids,
        unsigned short* __restrict__ slicecnt,   // [NSLICE][N_NODES] u16
        unsigned short* __restrict__ rank16) {   // [N_EDGES] u16 (RANK only)
    __shared__ unsigned int cnt[BUCK_W];
    int s = blockIdx.x >> 2;
    int b = blockIdx.x & 3;
    int b0 = b * BUCK_N;
    for (int w = threadIdx.x; w < BUCK_W; w += 512) cnt[w] = 0;
    __syncthreads();
    int base = s * SLICE_E;
    for (int i = threadIdx.x; i < SLICE_E; i += 512) {
        int e = base + i;
        int id = ids[e] - b0;
        if ((unsigned)id < (unsigned)BUCK_N) {
            unsigned int shift = (id & 1) * 16;
            unsigned int old = atomicAdd(&cnt[id >> 1], 1u << shift);
            if (RANK) rank16[e] = (unsigned short)((old >> shift) & 0xFFFFu);
        }
    }
    __syncthreads();
    unsigned int* row = (unsigned int*)(slicecnt + (size_t)s * N_NODES) + b * BUCK_W;
    for (int w = threadIdx.x; w < BUCK_W; w += 512) row[w] = cnt[w];
}

// per-node scan over slice counts: dst counts -> slice offsets (in place),
// in-degree + both norms (rsqrt fused). src counts only summed.
__global__ void scan_slices_kernel(unsigned short* __restrict__ scd,
                                   const unsigned short* __restrict__ scs,
                                   int* __restrict__ deg_int,
                                   float* __restrict__ norm_dst,
                                   float* __restrict__ norm_src) {
    int n = blockIdx.x * blockDim.x + threadIdx.x;
    if (n >= N_NODES) return;
    unsigned int tot = 0;
    for (int s = 0; s < NSLICE; ++s) {
        size_t idx = (size_t)s * N_NODES + n;
        unsigned int c = scd[idx];
        scd[idx] = (unsigned short)tot;
        tot += c;
    }
    deg_int[n] = (int)tot;
    norm_dst[n] = rsqrtf(fmaxf((float)tot, 1.0f));
    unsigned int so = 0;
    for (int s = 0; s < NSLICE; ++s) so += scs[(size_t)s * N_NODES + n];
    norm_src[n] = rsqrtf(fmaxf((float)so, 1.0f));
}

// ---------------- 3-phase device-wide exclusive scan of in-degrees ----------------

__global__ void block_sum_kernel(const int* __restrict__ deg_in, int* __restrict__ block_sums) {
    __shared__ int sdata[256];
    int t = threadIdx.x;
    int n = blockIdx.x * 256 + t;
    int v = (n < N_NODES) ? deg_in[n] : 0;
    sdata[t] = v;
    __syncthreads();
    for (int off = 128; off > 0; off >>= 1) {
        if (t < off) sdata[t] += sdata[t + off];
        __syncthreads();
    }
    if (t == 0) block_sums[blockIdx.x] = sdata[0];
}

__global__ void scan_blocks_kernel(const int* __restrict__ block_sums, int* __restrict__ block_off) {
    __shared__ int part[512];
    int t = threadIdx.x;
    int v = (t < NB_SCAN) ? block_sums[t] : 0;
    part[t] = v;
    __syncthreads();
    for (int off = 1; off < 512; off <<= 1) {
        int u = (t >= off) ? part[t - off] : 0;
        __syncthreads();
        part[t] += u;
        __syncthreads();
    }
    if (t < NB_SCAN) block_off[t] = part[t] - v;   // exclusive
}

__global__ void scatter_rowptr_kernel(const int* __restrict__ deg_in,
                                      const int* __restrict__ block_off,
                                      int* __restrict__ row_ptr) {
    __shared__ int part[256];
    int t = threadIdx.x;
    int n = blockIdx.x * 256 + t;
    int v = (n < N_NODES) ? deg_in[n] : 0;
    part[t] = v;
    __syncthreads();
    for (int off = 1; off < 256; off <<= 1) {
        int u = (t >= off) ? part[t - off] : 0;
        __syncthreads();
        part[t] += u;
        __syncthreads();
    }
    int excl = part[t] - v + block_off[blockIdx.x];
    if (n < N_NODES) row_ptr[n] = excl;
    if (n == N_NODES - 1) row_ptr[N_NODES] = excl + v;
}

// ---------------- atomic-free CSR fill ----------------
// slot = row_ptr[d] + sliceoff[slice][d] + rank-within-slice  (a permutation)

__global__ void fill_kernel(const int* __restrict__ src, const int* __restrict__ dst,
                            const float* __restrict__ ew,
                            const float* __restrict__ ns, const float* __restrict__ nd,
                            const int* __restrict__ row_ptr,
                            const unsigned short* __restrict__ sliceoff,
                            const unsigned short* __restrict__ rank16,
                            int2* __restrict__ epack) {
    int i = blockIdx.x * blockDim.x + threadIdx.x;
    int stride = gridDim.x * blockDim.x;
    for (int e = i; e < N_EDGES; e += stride) {
        int s = src[e], d = dst[e];
        int sl = e / SLICE_E;
        int slot = row_ptr[d] + (int)sliceoff[(size_t)sl * N_NODES + d] + (int)rank16[e];
        float c = ns[s] * ew[e] * nd[d];
        epack[slot] = make_int2(s, __float_as_int(c));
    }
}

// ---------------- dense transform: h = act(x [+b]) @ W ----------------

template <int DOUT, bool BIAS_RELU>
__global__ void matmul_kernel(const float* __restrict__ x, const float* __restrict__ W,
                              const float* __restrict__ bin, float* __restrict__ h) {
    __shared__ float Wl[64 * DOUT];
    int tid = threadIdx.x;
    for (int i = tid; i < 64 * DOUT; i += blockDim.x) Wl[i] = W[i];
    __syncthreads();

    int lane = tid & 63;
    int wid = tid >> 6;
    int wglobal = blockIdx.x * 4 + wid;
    int nwaves = gridDim.x * 4;
    int olane = lane & (DOUT - 1);

    float bv = 0.0f;
    if (BIAS_RELU) bv = bin[lane];

    for (int n = wglobal; n < N_NODES; n += nwaves) {
        float xv = x[n * 64 + lane];
        if (BIAS_RELU) xv = fmaxf(xv + bv, 0.0f);
        float acc = 0.0f;
#pragma unroll
        for (int k = 0; k < 64; ++k) {
            float xk = __shfl(xv, k);
            acc += xk * Wl[k * DOUT + olane];
        }
        if (lane < DOUT) h[n * DOUT + lane] = acc;
    }
}

// ---------------- CSR aggregation ----------------

template <int D, bool FINAL>
__global__ void csr_agg_kernel(const int* __restrict__ row_ptr,
                               const int2* __restrict__ epack,
                               const float* __restrict__ h,
                               const float* __restrict__ bias, float* __restrict__ out) {
    int tid = blockIdx.x * blockDim.x + threadIdx.x;
    int stride = gridDim.x * blockDim.x;
    int lane = threadIdx.x & (D - 1);
    int node0 = tid / D;
    int nstride = stride / D;
    for (int n = node0; n < N_NODES; n += nstride) {
        int s = row_ptr[n];
        int e = row_ptr[n + 1];
        float acc = 0.0f;
        int i = s;
        for (; i + 3 < e; i += 4) {
            int2 v0 = epack[i], v1 = epack[i + 1], v2 = epack[i + 2], v3 = epack[i + 3];
            float h0 = h[v0.x * D + lane];
            float h1 = h[v1.x * D + lane];
            float h2 = h[v2.x * D + lane];
            float h3 = h[v3.x * D + lane];
            acc += h0 * __int_as_float(v0.y) + h1 * __int_as_float(v1.y)
                 + h2 * __int_as_float(v2.y) + h3 * __int_as_float(v3.y);
        }
        for (; i < e; ++i) {
            int2 v = epack[i];
            acc += h[v.x * D + lane] * __int_as_float(v.y);
        }
        if (FINAL) out[n * D + lane] = acc + bias[lane];
        else       out[n * D + lane] = acc;
    }
}

extern "C" void kernel_launch(void* const* d_in, const int* in_sizes, int n_in,
                              void* d_out, int out_size, void* d_ws, size_t ws_size,
                              hipStream_t stream) {
    const float* features = (const float*)d_in[0];
    const float* ew       = (const float*)d_in[1];
    const int*   src      = (const int*)d_in[2];
    const int*   dst      = (const int*)d_in[3];
    const float* W1       = (const float*)d_in[4];
    const float* b1       = (const float*)d_in[5];
    const float* W2       = (const float*)d_in[6];
    const float* b2       = (const float*)d_in[7];
    const float* Wp       = (const float*)d_in[8];
    const float* bp       = (const float*)d_in[9];
    float* out = (float*)d_out;

    // workspace layout (explicit 4B-unit offsets)
    float* ws = (float*)d_ws;
    float* norm_src = ws;                             // @0        N
    float* norm_dst = ws + 100000;                    // @100000   N
    int*   deg_int  = (int*)(ws + 200000);            // @200000   N
    int*   row_ptr  = (int*)(ws + 300000);            // @300000   N+1
    int*   block_sums = (int*)(ws + 400002);          // @400002   NB_SCAN
    int*   block_off  = (int*)(ws + 400394);          // @400394   NB_SCAN
    unsigned short* rank16 = (unsigned short*)(ws + 400800); // 1.6M u16 = 800000 f
    int2*  epack = (int2*)(ws + 1200800);             // E int2 (byte off %8 == 0)
    float* bufA  = ws + 4400800;                      // N*64
    float* bufB  = ws + 10800800;                     // N*64

    // slice-count buffers alias bufA/bufB (dead until agg1/mm1 write them,
    // both after fill): [NSLICE][N_NODES] u16 = 12.8 MB each
    unsigned short* slicecnt_dst = (unsigned short*)bufA;  // becomes sliceoff in-place
    unsigned short* slicecnt_src = (unsigned short*)bufB;

    // ---- CSR + norms build: zero global atomics ----
    count_kernel<true><<<NSLICE * NBUCK, 512, 0, stream>>>(dst, slicecnt_dst, rank16);
    count_kernel<false><<<NSLICE * NBUCK, 512, 0, stream>>>(src, slicecnt_src, nullptr);
    scan_slices_kernel<<<NB_SCAN, 256, 0, stream>>>(slicecnt_dst, slicecnt_src,
                                                    deg_int, norm_dst, norm_src);
    block_sum_kernel<<<NB_SCAN, 256, 0, stream>>>(deg_int, block_sums);
    scan_blocks_kernel<<<1, 512, 0, stream>>>(block_sums, block_off);
    scatter_rowptr_kernel<<<NB_SCAN, 256, 0, stream>>>(deg_int, block_off, row_ptr);
    fill_kernel<<<2048, 256, 0, stream>>>(src, dst, ew, norm_src, norm_dst,
                                          row_ptr, slicecnt_dst, rank16, epack);

    // ---- layer 1: bufA = A * (features @ W1)   (bias+relu deferred)
    matmul_kernel<64, false><<<1024, 256, 0, stream>>>(features, W1, nullptr, bufB);
    csr_agg_kernel<64, false><<<4096, 256, 0, stream>>>(row_ptr, epack, bufB, nullptr, bufA);

    // ---- layer 2: bufA = A * (relu(bufA + b1) @ W2)
    matmul_kernel<64, true><<<1024, 256, 0, stream>>>(bufA, W2, b1, bufB);
    csr_agg_kernel<64, false><<<4096, 256, 0, stream>>>(row_ptr, epack, bufB, nullptr, bufA);

    // ---- layer 3: out = A * (relu(bufA + b2) @ Wp) + bp
    matmul_kernel<32, true><<<1024, 256, 0, stream>>>(bufA, Wp, b2, bufB);
    csr_agg_kernel<32, true><<<4096, 256, 0, stream>>>(row_ptr, epack, bufB, bp, out);
}

// Round 7
// 516.291 us; speedup vs baseline: 1.3490x; 1.0361x over previous
//
#include <hip/hip_runtime.h>

#define N_NODES 100000
#define N_EDGES 1600000
#define NB_SCAN 391    // ceil(N_NODES / 256)
#define NSLICE 64      // edge slices
#define SLICE_E 25000  // N_EDGES / NSLICE
#define NBUCK 4        // node buckets
#define BUCK_N 25000   // nodes per bucket (N_NODES / NBUCK)
#define BUCK_W 12500   // uint32 words per bucket (2x uint16 packed)

// ---------------- LDS-bucketed histogram (no global atomics) ----------------

template <bool RANK>
__global__ void __launch_bounds__(512) count_kernel(
        const int* __restrict__ ids,
        unsigned short* __restrict__ slicecnt,   // [NSLICE][N_NODES] u16
        unsigned short* __restrict__ rank16) {   // [N_EDGES] u16 (RANK only)
    __shared__ unsigned int cnt[BUCK_W];
    int s = blockIdx.x >> 2;
    int b = blockIdx.x & 3;
    int b0 = b * BUCK_N;
    for (int w = threadIdx.x; w < BUCK_W; w += 512) cnt[w] = 0;
    __syncthreads();
    int base = s * SLICE_E;
    for (int i = threadIdx.x; i < SLICE_E; i += 512) {
        int e = base + i;
        int id = ids[e] - b0;
        if ((unsigned)id < (unsigned)BUCK_N) {
            unsigned int shift = (id & 1) * 16;
            unsigned int old = atomicAdd(&cnt[id >> 1], 1u << shift);
            if (RANK) rank16[e] = (unsigned short)((old >> shift) & 0xFFFFu);
        }
    }
    __syncthreads();
    unsigned int* row = (unsigned int*)(slicecnt + (size_t)s * N_NODES) + b * BUCK_W;
    for (int w = threadIdx.x; w < BUCK_W; w += 512) row[w] = cnt[w];
}

// per-node scan over slice counts: dst counts -> slice offsets (in place),
// in-degree + both norms (rsqrt fused). src counts only summed.
__global__ void scan_slices_kernel(unsigned short* __restrict__ scd,
                                   const unsigned short* __restrict__ scs,
                                   int* __restrict__ deg_int,
                                   float* __restrict__ norm_dst,
                                   float* __restrict__ norm_src) {
    int n = blockIdx.x * blockDim.x + threadIdx.x;
    if (n >= N_NODES) return;
    unsigned int tot = 0;
    for (int s = 0; s < NSLICE; ++s) {
        size_t idx = (size_t)s * N_NODES + n;
        unsigned int c = scd[idx];
        scd[idx] = (unsigned short)tot;
        tot += c;
    }
    deg_int[n] = (int)tot;
    norm_dst[n] = rsqrtf(fmaxf((float)tot, 1.0f));
    unsigned int so = 0;
    for (int s = 0; s < NSLICE; ++s) so += scs[(size_t)s * N_NODES + n];
    norm_src[n] = rsqrtf(fmaxf((float)so, 1.0f));
}

// ---------------- 3-phase device-wide exclusive scan of in-degrees ----------------

__global__ void block_sum_kernel(const int* __restrict__ deg_in, int* __restrict__ block_sums) {
    __shared__ int sdata[256];
    int t = threadIdx.x;
    int n = blockIdx.x * 256 + t;
    int v = (n < N_NODES) ? deg_in[n] : 0;
    sdata[t] = v;
    __syncthreads();
    for (int off = 128; off > 0; off >>= 1) {
        if (t < off) sdata[t] += sdata[t + off];
        __syncthreads();
    }
    if (t == 0) block_sums[blockIdx.x] = sdata[0];
}

__global__ void scan_blocks_kernel(const int* __restrict__ block_sums, int* __restrict__ block_off) {
    __shared__ int part[512];
    int t = threadIdx.x;
    int v = (t < NB_SCAN) ? block_sums[t] : 0;
    part[t] = v;
    __syncthreads();
    for (int off = 1; off < 512; off <<= 1) {
        int u = (t >= off) ? part[t - off] : 0;
        __syncthreads();
        part[t] += u;
        __syncthreads();
    }
    if (t < NB_SCAN) block_off[t] = part[t] - v;   // exclusive
}

__global__ void scatter_rowptr_kernel(const int* __restrict__ deg_in,
                                      const int* __restrict__ block_off,
                                      int* __restrict__ row_ptr) {
    __shared__ int part[256];
    int t = threadIdx.x;
    int n = blockIdx.x * 256 + t;
    int v = (n < N_NODES) ? deg_in[n] : 0;
    part[t] = v;
    __syncthreads();
    for (int off = 1; off < 256; off <<= 1) {
        int u = (t >= off) ? part[t - off] : 0;
        __syncthreads();
        part[t] += u;
        __syncthreads();
    }
    int excl = part[t] - v + block_off[blockIdx.x];
    if (n < N_NODES) row_ptr[n] = excl;
    if (n == N_NODES - 1) row_ptr[N_NODES] = excl + v;
}

// ---------------- atomic-free CSR fill ----------------
// slot = row_ptr[d] + sliceoff[slice][d] + rank-within-slice  (a permutation)

__global__ void fill_kernel(const int* __restrict__ src, const int* __restrict__ dst,
                            const float* __restrict__ ew,
                            const float* __restrict__ ns, const float* __restrict__ nd,
                            const int* __restrict__ row_ptr,
                            const unsigned short* __restrict__ sliceoff,
                            const unsigned short* __restrict__ rank16,
                            int2* __restrict__ epack) {
    int i = blockIdx.x * blockDim.x + threadIdx.x;
    int stride = gridDim.x * blockDim.x;
    for (int e = i; e < N_EDGES; e += stride) {
        int s = src[e], d = dst[e];
        int sl = e / SLICE_E;
        int slot = row_ptr[d] + (int)sliceoff[(size_t)sl * N_NODES + d] + (int)rank16[e];
        float c = ns[s] * ew[e] * nd[d];
        epack[slot] = make_int2(s, __float_as_int(c));
    }
}

// ---------------- dense transform: h = act(x [+b]) @ W ----------------
// Wave per node. W column held in 64 VGPRs (loaded once, static indices).
// Inner loop: broadcast wave-uniform x[n][k] + fmac, two acc chains for ILP.
// No LDS in the hot loop (R6 showed the Wl ds_read + shfl serial chain was
// a ~120cyc/iter latency wall -> 109us).

template <int DOUT, bool BIAS_RELU>
__global__ void matmul_kernel(const float* __restrict__ x, const float* __restrict__ W,
                              const float* __restrict__ bin, float* __restrict__ h) {
    int tid = threadIdx.x;
    int lane = tid & 63;
    int olane = lane & (DOUT - 1);

    float Wc[64];
#pragma unroll
    for (int k = 0; k < 64; ++k) Wc[k] = W[k * DOUT + olane];   // coalesced per k

    float bv = 0.0f;
    if (BIAS_RELU) bv = bin[lane];

    int wid = tid >> 6;
    int wglobal = blockIdx.x * (blockDim.x >> 6) + wid;
    int nwaves = gridDim.x * (blockDim.x >> 6);

    int n = wglobal;
    if (n >= N_NODES) return;
    float xv = x[n * 64 + lane];
    for (; n < N_NODES; n += nwaves) {
        float xcur = xv;
        int n2 = n + nwaves;
        if (n2 < N_NODES) xv = x[n2 * 64 + lane];   // prefetch next node
        if (BIAS_RELU) xcur = fmaxf(xcur + bv, 0.0f);
        float a0 = 0.0f, a1 = 0.0f;
#pragma unroll
        for (int k = 0; k < 64; k += 2) {
            a0 = fmaf(__shfl(xcur, k),     Wc[k],     a0);
            a1 = fmaf(__shfl(xcur, k + 1), Wc[k + 1], a1);
        }
        if (lane < DOUT) h[n * DOUT + lane] = a0 + a1;
    }
}

// ---------------- CSR aggregation ----------------

template <int D, bool FINAL>
__global__ void csr_agg_kernel(const int* __restrict__ row_ptr,
                               const int2* __restrict__ epack,
                               const float* __restrict__ h,
                               const float* __restrict__ bias, float* __restrict__ out) {
    int tid = blockIdx.x * blockDim.x + threadIdx.x;
    int stride = gridDim.x * blockDim.x;
    int lane = threadIdx.x & (D - 1);
    int node0 = tid / D;
    int nstride = stride / D;
    for (int n = node0; n < N_NODES; n += nstride) {
        int s = row_ptr[n];
        int e = row_ptr[n + 1];
        float acc = 0.0f;
        int i = s;
        for (; i + 3 < e; i += 4) {
            int2 v0 = epack[i], v1 = epack[i + 1], v2 = epack[i + 2], v3 = epack[i + 3];
            float h0 = h[v0.x * D + lane];
            float h1 = h[v1.x * D + lane];
            float h2 = h[v2.x * D + lane];
            float h3 = h[v3.x * D + lane];
            acc += h0 * __int_as_float(v0.y) + h1 * __int_as_float(v1.y)
                 + h2 * __int_as_float(v2.y) + h3 * __int_as_float(v3.y);
        }
        for (; i < e; ++i) {
            int2 v = epack[i];
            acc += h[v.x * D + lane] * __int_as_float(v.y);
        }
        if (FINAL) out[n * D + lane] = acc + bias[lane];
        else       out[n * D + lane] = acc;
    }
}

extern "C" void kernel_launch(void* const* d_in, const int* in_sizes, int n_in,
                              void* d_out, int out_size, void* d_ws, size_t ws_size,
                              hipStream_t stream) {
    const float* features = (const float*)d_in[0];
    const float* ew       = (const float*)d_in[1];
    const int*   src      = (const int*)d_in[2];
    const int*   dst      = (const int*)d_in[3];
    const float* W1       = (const float*)d_in[4];
    const float* b1       = (const float*)d_in[5];
    const float* W2       = (const float*)d_in[6];
    const float* b2       = (const float*)d_in[7];
    const float* Wp       = (const float*)d_in[8];
    const float* bp       = (const float*)d_in[9];
    float* out = (float*)d_out;

    // workspace layout (explicit 4B-unit offsets)
    float* ws = (float*)d_ws;
    float* norm_src = ws;                             // @0        N
    float* norm_dst = ws + 100000;                    // @100000   N
    int*   deg_int  = (int*)(ws + 200000);            // @200000   N
    int*   row_ptr  = (int*)(ws + 300000);            // @300000   N+1
    int*   block_sums = (int*)(ws + 400002);          // @400002   NB_SCAN
    int*   block_off  = (int*)(ws + 400394);          // @400394   NB_SCAN
    unsigned short* rank16 = (unsigned short*)(ws + 400800); // 1.6M u16 = 800000 f
    int2*  epack = (int2*)(ws + 1200800);             // E int2 (byte off %8 == 0)
    float* bufA  = ws + 4400800;                      // N*64
    float* bufB  = ws + 10800800;                     // N*64

    // slice-count buffers alias bufA/bufB (dead until agg1/mm1 write them)
    unsigned short* slicecnt_dst = (unsigned short*)bufA;  // becomes sliceoff in-place
    unsigned short* slicecnt_src = (unsigned short*)bufB;

    // ---- CSR + norms build: zero global atomics ----
    count_kernel<true><<<NSLICE * NBUCK, 512, 0, stream>>>(dst, slicecnt_dst, rank16);
    count_kernel<false><<<NSLICE * NBUCK, 512, 0, stream>>>(src, slicecnt_src, nullptr);
    scan_slices_kernel<<<NB_SCAN, 256, 0, stream>>>(slicecnt_dst, slicecnt_src,
                                                    deg_int, norm_dst, norm_src);
    block_sum_kernel<<<NB_SCAN, 256, 0, stream>>>(deg_int, block_sums);
    scan_blocks_kernel<<<1, 512, 0, stream>>>(block_sums, block_off);
    scatter_rowptr_kernel<<<NB_SCAN, 256, 0, stream>>>(deg_int, block_off, row_ptr);
    fill_kernel<<<2048, 256, 0, stream>>>(src, dst, ew, norm_src, norm_dst,
                                          row_ptr, slicecnt_dst, rank16, epack);

    // ---- layer 1: bufA = A * (features @ W1)   (bias+relu deferred)
    matmul_kernel<64, false><<<1024, 256, 0, stream>>>(features, W1, nullptr, bufB);
    csr_agg_kernel<64, false><<<4096, 256, 0, stream>>>(row_ptr, epack, bufB, nullptr, bufA);

    // ---- layer 2: bufA = A * (relu(bufA + b1) @ W2)
    matmul_kernel<64, true><<<1024, 256, 0, stream>>>(bufA, W2, b1, bufB);
    csr_agg_kernel<64, false><<<4096, 256, 0, stream>>>(row_ptr, epack, bufB, nullptr, bufA);

    // ---- layer 3: out = A * (relu(bufA + b2) @ Wp) + bp
    matmul_kernel<32, true><<<1024, 256, 0, stream>>>(bufA, Wp, b2, bufB);
    csr_agg_kernel<32, true><<<4096, 256, 0, stream>>>(row_ptr, epack, bufB, bp, out);
}

// Round 8
// 340.452 us; speedup vs baseline: 2.0458x; 1.5165x over previous
//
#include <hip/hip_runtime.h>

#define N_NODES 100000
#define N_EDGES 1600000
#define NB_SCAN 391    // ceil(N_NODES / 256)
#define NSLICE 64      // edge slices
#define SLICE_E 25000  // N_EDGES / NSLICE
#define NBUCK 4        // node buckets
#define BUCK_N 25000   // nodes per bucket (N_NODES / NBUCK)
#define BUCK_W 12500   // uint32 words per bucket (2x uint16 packed)

// ---------------- LDS-bucketed histogram (no global atomics) ----------------

template <bool RANK>
__global__ void __launch_bounds__(512) count_kernel(
        const int* __restrict__ ids,
        unsigned short* __restrict__ slicecnt,   // [NSLICE][N_NODES] u16
        unsigned short* __restrict__ rank16) {   // [N_EDGES] u16 (RANK only)
    __shared__ unsigned int cnt[BUCK_W];
    int s = blockIdx.x >> 2;
    int b = blockIdx.x & 3;
    int b0 = b * BUCK_N;
    for (int w = threadIdx.x; w < BUCK_W; w += 512) cnt[w] = 0;
    __syncthreads();
    int base = s * SLICE_E;
    for (int i = threadIdx.x; i < SLICE_E; i += 512) {
        int e = base + i;
        int id = ids[e] - b0;
        if ((unsigned)id < (unsigned)BUCK_N) {
            unsigned int shift = (id & 1) * 16;
            unsigned int old = atomicAdd(&cnt[id >> 1], 1u << shift);
            if (RANK) rank16[e] = (unsigned short)((old >> shift) & 0xFFFFu);
        }
    }
    __syncthreads();
    unsigned int* row = (unsigned int*)(slicecnt + (size_t)s * N_NODES) + b * BUCK_W;
    for (int w = threadIdx.x; w < BUCK_W; w += 512) row[w] = cnt[w];
}

// per-node scan over slice counts: dst counts -> slice offsets (in place),
// in-degree + both norms (rsqrt fused). src counts only summed.
__global__ void scan_slices_kernel(unsigned short* __restrict__ scd,
                                   const unsigned short* __restrict__ scs,
                                   int* __restrict__ deg_int,
                                   float* __restrict__ norm_dst,
                                   float* __restrict__ norm_src) {
    int n = blockIdx.x * blockDim.x + threadIdx.x;
    if (n >= N_NODES) return;
    unsigned int tot = 0;
    for (int s = 0; s < NSLICE; ++s) {
        size_t idx = (size_t)s * N_NODES + n;
        unsigned int c = scd[idx];
        scd[idx] = (unsigned short)tot;
        tot += c;
    }
    deg_int[n] = (int)tot;
    norm_dst[n] = rsqrtf(fmaxf((float)tot, 1.0f));
    unsigned int so = 0;
    for (int s = 0; s < NSLICE; ++s) so += scs[(size_t)s * N_NODES + n];
    norm_src[n] = rsqrtf(fmaxf((float)so, 1.0f));
}

// ---------------- 3-phase device-wide exclusive scan of in-degrees ----------------

__global__ void block_sum_kernel(const int* __restrict__ deg_in, int* __restrict__ block_sums) {
    __shared__ int sdata[256];
    int t = threadIdx.x;
    int n = blockIdx.x * 256 + t;
    int v = (n < N_NODES) ? deg_in[n] : 0;
    sdata[t] = v;
    __syncthreads();
    for (int off = 128; off > 0; off >>= 1) {
        if (t < off) sdata[t] += sdata[t + off];
        __syncthreads();
    }
    if (t == 0) block_sums[blockIdx.x] = sdata[0];
}

__global__ void scan_blocks_kernel(const int* __restrict__ block_sums, int* __restrict__ block_off) {
    __shared__ int part[512];
    int t = threadIdx.x;
    int v = (t < NB_SCAN) ? block_sums[t] : 0;
    part[t] = v;
    __syncthreads();
    for (int off = 1; off < 512; off <<= 1) {
        int u = (t >= off) ? part[t - off] : 0;
        __syncthreads();
        part[t] += u;
        __syncthreads();
    }
    if (t < NB_SCAN) block_off[t] = part[t] - v;   // exclusive
}

__global__ void scatter_rowptr_kernel(const int* __restrict__ deg_in,
                                      const int* __restrict__ block_off,
                                      int* __restrict__ row_ptr) {
    __shared__ int part[256];
    int t = threadIdx.x;
    int n = blockIdx.x * 256 + t;
    int v = (n < N_NODES) ? deg_in[n] : 0;
    part[t] = v;
    __syncthreads();
    for (int off = 1; off < 256; off <<= 1) {
        int u = (t >= off) ? part[t - off] : 0;
        __syncthreads();
        part[t] += u;
        __syncthreads();
    }
    int excl = part[t] - v + block_off[blockIdx.x];
    if (n < N_NODES) row_ptr[n] = excl;
    if (n == N_NODES - 1) row_ptr[N_NODES] = excl + v;
}

// ---------------- atomic-free CSR fill ----------------
// slot = row_ptr[d] + sliceoff[slice][d] + rank-within-slice  (a permutation)

__global__ void fill_kernel(const int* __restrict__ src, const int* __restrict__ dst,
                            const float* __restrict__ ew,
                            const float* __restrict__ ns, const float* __restrict__ nd,
                            const int* __restrict__ row_ptr,
                            const unsigned short* __restrict__ sliceoff,
                            const unsigned short* __restrict__ rank16,
                            int2* __restrict__ epack) {
    int i = blockIdx.x * blockDim.x + threadIdx.x;
    int stride = gridDim.x * blockDim.x;
    for (int e = i; e < N_EDGES; e += stride) {
        int s = src[e], d = dst[e];
        int sl = e / SLICE_E;
        int slot = row_ptr[d] + (int)sliceoff[(size_t)sl * N_NODES + d] + (int)rank16[e];
        float c = ns[s] * ew[e] * nd[d];
        epack[slot] = make_int2(s, __float_as_int(c));
    }
}

// ---------------- dense transform: h = act(x [+b]) @ W ----------------
// LDS-tiled fp32 GEMM, 4x4 register tile per thread (outer product -> high
// ILP, ~40 VGPR, no spill; R7's Wc[64]-in-VGPR variant spilled at VGPR=64).
// X-tile row stride 65 floats: ng-lanes hit distinct banks (4*65 % 32 == 4).

template <int BM, int DOUT, bool BIAS_RELU>
__global__ void __launch_bounds__(256) matmul_kernel(
        const float* __restrict__ x, const float* __restrict__ W,
        const float* __restrict__ bin, float* __restrict__ h) {
    constexpr int S = 65;           // Xs row stride (floats)
    constexpr int CG = DOUT / 4;    // column groups of 4
    __shared__ float Xs[BM * S];
    __shared__ float Ws[64 * DOUT];
    int tid = threadIdx.x;
    int n0 = blockIdx.x * BM;

    // stage W (row-major [64][DOUT])
    for (int i = tid; i < 16 * DOUT; i += 256)
        ((float4*)Ws)[i] = ((const float4*)W)[i];

    // stage X tile with fused bias+relu; b32 writes (S=65 rows not 16B-aligned)
    float4 bv4;
    if (BIAS_RELU) bv4 = ((const float4*)bin)[tid & 15];
    int c0 = (tid & 15) * 4;
    for (int r = tid >> 4; r < BM; r += 16) {
        int n = n0 + r;
        int nc = n < N_NODES ? n : N_NODES - 1;
        float4 v = ((const float4*)(x + (size_t)nc * 64))[tid & 15];
        if (BIAS_RELU) {
            v.x = fmaxf(v.x + bv4.x, 0.0f);
            v.y = fmaxf(v.y + bv4.y, 0.0f);
            v.z = fmaxf(v.z + bv4.z, 0.0f);
            v.w = fmaxf(v.w + bv4.w, 0.0f);
        }
        Xs[r * S + c0]     = v.x;
        Xs[r * S + c0 + 1] = v.y;
        Xs[r * S + c0 + 2] = v.z;
        Xs[r * S + c0 + 3] = v.w;
    }
    __syncthreads();

    int cg = tid % CG;
    int ng = tid / CG;

    float acc[4][4];
#pragma unroll
    for (int i = 0; i < 4; ++i)
#pragma unroll
        for (int j = 0; j < 4; ++j) acc[i][j] = 0.0f;

#pragma unroll 16
    for (int k = 0; k < 64; ++k) {
        float4 wk = *(const float4*)(&Ws[k * DOUT + cg * 4]);
        float xk[4];
#pragma unroll
        for (int i = 0; i < 4; ++i) xk[i] = Xs[(ng * 4 + i) * S + k];
#pragma unroll
        for (int i = 0; i < 4; ++i) {
            acc[i][0] = fmaf(xk[i], wk.x, acc[i][0]);
            acc[i][1] = fmaf(xk[i], wk.y, acc[i][1]);
            acc[i][2] = fmaf(xk[i], wk.z, acc[i][2]);
            acc[i][3] = fmaf(xk[i], wk.w, acc[i][3]);
        }
    }

#pragma unroll
    for (int i = 0; i < 4; ++i) {
        int n = n0 + ng * 4 + i;
        if (n < N_NODES)
            *(float4*)(&h[(size_t)n * DOUT + cg * 4]) =
                make_float4(acc[i][0], acc[i][1], acc[i][2], acc[i][3]);
    }
}

// ---------------- CSR aggregation ----------------

template <int D, bool FINAL>
__global__ void csr_agg_kernel(const int* __restrict__ row_ptr,
                               const int2* __restrict__ epack,
                               const float* __restrict__ h,
                               const float* __restrict__ bias, float* __restrict__ out) {
    int tid = blockIdx.x * blockDim.x + threadIdx.x;
    int stride = gridDim.x * blockDim.x;
    int lane = threadIdx.x & (D - 1);
    int node0 = tid / D;
    int nstride = stride / D;
    for (int n = node0; n < N_NODES; n += nstride) {
        int s = row_ptr[n];
        int e = row_ptr[n + 1];
        float acc = 0.0f;
        int i = s;
        for (; i + 3 < e; i += 4) {
            int2 v0 = epack[i], v1 = epack[i + 1], v2 = epack[i + 2], v3 = epack[i + 3];
            float h0 = h[v0.x * D + lane];
            float h1 = h[v1.x * D + lane];
            float h2 = h[v2.x * D + lane];
            float h3 = h[v3.x * D + lane];
            acc += h0 * __int_as_float(v0.y) + h1 * __int_as_float(v1.y)
                 + h2 * __int_as_float(v2.y) + h3 * __int_as_float(v3.y);
        }
        for (; i < e; ++i) {
            int2 v = epack[i];
            acc += h[v.x * D + lane] * __int_as_float(v.y);
        }
        if (FINAL) out[n * D + lane] = acc + bias[lane];
        else       out[n * D + lane] = acc;
    }
}

extern "C" void kernel_launch(void* const* d_in, const int* in_sizes, int n_in,
                              void* d_out, int out_size, void* d_ws, size_t ws_size,
                              hipStream_t stream) {
    const float* features = (const float*)d_in[0];
    const float* ew       = (const float*)d_in[1];
    const int*   src      = (const int*)d_in[2];
    const int*   dst      = (const int*)d_in[3];
    const float* W1       = (const float*)d_in[4];
    const float* b1       = (const float*)d_in[5];
    const float* W2       = (const float*)d_in[6];
    const float* b2       = (const float*)d_in[7];
    const float* Wp       = (const float*)d_in[8];
    const float* bp       = (const float*)d_in[9];
    float* out = (float*)d_out;

    // workspace layout (explicit 4B-unit offsets)
    float* ws = (float*)d_ws;
    float* norm_src = ws;                             // @0        N
    float* norm_dst = ws + 100000;                    // @100000   N
    int*   deg_int  = (int*)(ws + 200000);            // @200000   N
    int*   row_ptr  = (int*)(ws + 300000);            // @300000   N+1
    int*   block_sums = (int*)(ws + 400002);          // @400002   NB_SCAN
    int*   block_off  = (int*)(ws + 400394);          // @400394   NB_SCAN
    unsigned short* rank16 = (unsigned short*)(ws + 400800); // 1.6M u16 = 800000 f
    int2*  epack = (int2*)(ws + 1200800);             // E int2 (byte off %8 == 0)
    float* bufA  = ws + 4400800;                      // N*64
    float* bufB  = ws + 10800800;                     // N*64

    // slice-count buffers alias bufA/bufB (dead until agg1/mm1 write them)
    unsigned short* slicecnt_dst = (unsigned short*)bufA;  // becomes sliceoff in-place
    unsigned short* slicecnt_src = (unsigned short*)bufB;

    // ---- CSR + norms build: zero global atomics ----
    count_kernel<true><<<NSLICE * NBUCK, 512, 0, stream>>>(dst, slicecnt_dst, rank16);
    count_kernel<false><<<NSLICE * NBUCK, 512, 0, stream>>>(src, slicecnt_src, nullptr);
    scan_slices_kernel<<<NB_SCAN, 256, 0, stream>>>(slicecnt_dst, slicecnt_src,
                                                    deg_int, norm_dst, norm_src);
    block_sum_kernel<<<NB_SCAN, 256, 0, stream>>>(deg_int, block_sums);
    scan_blocks_kernel<<<1, 512, 0, stream>>>(block_sums, block_off);
    scatter_rowptr_kernel<<<NB_SCAN, 256, 0, stream>>>(deg_int, block_off, row_ptr);
    fill_kernel<<<2048, 256, 0, stream>>>(src, dst, ew, norm_src, norm_dst,
                                          row_ptr, slicecnt_dst, rank16, epack);

    // ---- layer 1: bufA = A * (features @ W1)   (bias+relu deferred)
    matmul_kernel<64, 64, false><<<1563, 256, 0, stream>>>(features, W1, nullptr, bufB);
    csr_agg_kernel<64, false><<<4096, 256, 0, stream>>>(row_ptr, epack, bufB, nullptr, bufA);

    // ---- layer 2: bufA = A * (relu(bufA + b1) @ W2)
    matmul_kernel<64, 64, true><<<1563, 256, 0, stream>>>(bufA, W2, b1, bufB);
    csr_agg_kernel<64, false><<<4096, 256, 0, stream>>>(row_ptr, epack, bufB, nullptr, bufA);

    // ---- layer 3: out = A * (relu(bufA + b2) @ Wp) + bp
    matmul_kernel<128, 32, true><<<782, 256, 0, stream>>>(bufA, Wp, b2, bufB);
    csr_agg_kernel<32, true><<<4096, 256, 0, stream>>>(row_ptr, epack, bufB, bp, out);
}